// Round 7
// baseline (3602.489 us; speedup 1.0000x reference)
//
#include <hip/hip_runtime.h>
#include <cstddef>
#include <cstdint>

#define BATCH   2
#define SEQLEN  2048
#define DMODEL  2048
#define DINNER  4096
#define NHEADS  64
#define HEADDIM 64
#define DSTATE  128
#define DCONV   4
#define CHUNKSZ 256
#define NCHUNK  (SEQLEN / CHUNKSZ)                 // 8
#define CONVDIM (DINNER + 2 * DSTATE)              // 4352
#define DINPROJ (2 * DINNER + 2 * DSTATE + NHEADS) // 8512
#define BL      (BATCH * SEQLEN)                   // 4096
#define EPSV    1e-5f

__device__ __forceinline__ float sigmoidf_(float x) { return 1.f / (1.f + expf(-x)); }

// ---------------------------------------------------------------------------
// in_proj GEMM with split epilogue:
//   [BL, DINPROJ] = u[BL, DMODEL] * Wp[DINPROJ, DMODEL]^T
// cols [0,4096) -> zbuf, [4096,8448) -> xbc, [8448,8512) -> dtraw
// 128x128 tile, BK=16, 256 threads, 8x8 micro-tile.
// ---------------------------------------------------------------------------
__global__ __launch_bounds__(256) void gemm_inproj(const float* __restrict__ A,
                                                   const float* __restrict__ B,
                                                   float* __restrict__ zbuf,
                                                   float* __restrict__ xbc,
                                                   float* __restrict__ dtraw) {
  __shared__ __align__(16) float As[16][136];
  __shared__ __align__(16) float Bs[16][136];
  const int bm = blockIdx.y * 128;
  const int bn = blockIdx.x * 128;
  const int tid = threadIdx.x;
  const int tx = tid & 15, ty = tid >> 4;
  const int K = DMODEL;
  float acc[8][8] = {};
  for (int k0 = 0; k0 < K; k0 += 16) {
#pragma unroll
    for (int t = 0; t < 2; ++t) {
      int idx = tid + t * 256;
      int row = idx >> 2;
      int kq = (idx & 3) << 2;
      float4 av = *(const float4*)(A + (size_t)(bm + row) * K + k0 + kq);
      As[kq + 0][row] = av.x; As[kq + 1][row] = av.y;
      As[kq + 2][row] = av.z; As[kq + 3][row] = av.w;
      float4 bv = make_float4(0.f, 0.f, 0.f, 0.f);
      if (bn + row < DINPROJ) bv = *(const float4*)(B + (size_t)(bn + row) * K + k0 + kq);
      Bs[kq + 0][row] = bv.x; Bs[kq + 1][row] = bv.y;
      Bs[kq + 2][row] = bv.z; Bs[kq + 3][row] = bv.w;
    }
    __syncthreads();
#pragma unroll
    for (int kk = 0; kk < 16; ++kk) {
      float a[8], b[8];
      *(float4*)&a[0] = *(const float4*)&As[kk][ty * 8];
      *(float4*)&a[4] = *(const float4*)&As[kk][ty * 8 + 4];
      *(float4*)&b[0] = *(const float4*)&Bs[kk][tx * 8];
      *(float4*)&b[4] = *(const float4*)&Bs[kk][tx * 8 + 4];
#pragma unroll
      for (int i = 0; i < 8; ++i)
#pragma unroll
        for (int j = 0; j < 8; ++j)
          acc[i][j] = fmaf(a[i], b[j], acc[i][j]);
    }
    __syncthreads();
  }
#pragma unroll
  for (int i = 0; i < 8; ++i) {
    int grow = bm + ty * 8 + i;
#pragma unroll
    for (int jq = 0; jq < 8; jq += 4) {
      int col = bn + tx * 8 + jq;
      if (col < DINPROJ) {
        float4 v = make_float4(acc[i][jq], acc[i][jq + 1], acc[i][jq + 2], acc[i][jq + 3]);
        if (col < DINNER)
          *(float4*)(zbuf + (size_t)grow * DINNER + col) = v;
        else if (col < DINNER + CONVDIM)
          *(float4*)(xbc + (size_t)grow * CONVDIM + (col - DINNER)) = v;
        else
          *(float4*)(dtraw + (size_t)grow * NHEADS + (col - DINNER - CONVDIM)) = v;
      }
    }
  }
}

// ---------------------------------------------------------------------------
// fp32 GEMM: C[M,N] = A[M,K] * B[N,K]^T  (generic, used for out_proj)
// ---------------------------------------------------------------------------
__global__ __launch_bounds__(256) void gemm_bt128(const float* __restrict__ A,
                                                  const float* __restrict__ B,
                                                  float* __restrict__ C,
                                                  int M, int N, int K) {
  __shared__ __align__(16) float As[16][136];
  __shared__ __align__(16) float Bs[16][136];
  const int bm = blockIdx.y * 128;
  const int bn = blockIdx.x * 128;
  const int tid = threadIdx.x;
  const int tx = tid & 15, ty = tid >> 4;
  float acc[8][8] = {};
  for (int k0 = 0; k0 < K; k0 += 16) {
#pragma unroll
    for (int t = 0; t < 2; ++t) {
      int idx = tid + t * 256;
      int row = idx >> 2;
      int kq = (idx & 3) << 2;
      float4 av = *(const float4*)(A + (size_t)(bm + row) * K + k0 + kq);
      As[kq + 0][row] = av.x; As[kq + 1][row] = av.y;
      As[kq + 2][row] = av.z; As[kq + 3][row] = av.w;
      float4 bv = make_float4(0.f, 0.f, 0.f, 0.f);
      if (bn + row < N) bv = *(const float4*)(B + (size_t)(bn + row) * K + k0 + kq);
      Bs[kq + 0][row] = bv.x; Bs[kq + 1][row] = bv.y;
      Bs[kq + 2][row] = bv.z; Bs[kq + 3][row] = bv.w;
    }
    __syncthreads();
#pragma unroll
    for (int kk = 0; kk < 16; ++kk) {
      float a[8], b[8];
      *(float4*)&a[0] = *(const float4*)&As[kk][ty * 8];
      *(float4*)&a[4] = *(const float4*)&As[kk][ty * 8 + 4];
      *(float4*)&b[0] = *(const float4*)&Bs[kk][tx * 8];
      *(float4*)&b[4] = *(const float4*)&Bs[kk][tx * 8 + 4];
#pragma unroll
      for (int i = 0; i < 8; ++i)
#pragma unroll
        for (int j = 0; j < 8; ++j)
          acc[i][j] = fmaf(a[i], b[j], acc[i][j]);
    }
    __syncthreads();
  }
#pragma unroll
  for (int i = 0; i < 8; ++i) {
    size_t row = (size_t)(bm + ty * 8 + i) * N;
#pragma unroll
    for (int jq = 0; jq < 8; jq += 4) {
      int col = bn + tx * 8 + jq;
      if (col < N) {
        float4 v = make_float4(acc[i][jq], acc[i][jq + 1], acc[i][jq + 2], acc[i][jq + 3]);
        *(float4*)(C + row + col) = v;
      }
    }
  }
}

// ---------------------------------------------------------------------------
// Causal depthwise conv (k=4) + SiLU + split into x / B / C
// ---------------------------------------------------------------------------
__global__ __launch_bounds__(256) void conv_silu_split(const float* __restrict__ xbc,
                                                       const float* __restrict__ cw,
                                                       const float* __restrict__ cb,
                                                       float* __restrict__ xb,
                                                       float* __restrict__ bbuf,
                                                       float* __restrict__ cbuf) {
  int idx = blockIdx.x * 256 + threadIdx.x;
  if (idx >= BL * CONVDIM) return;
  int ch = idx % CONVDIM;
  int bl = idx / CONVDIM;
  int l = bl & (SEQLEN - 1);
  int b = bl / SEQLEN;
  float acc = cb[ch];
#pragma unroll
  for (int k = 0; k < DCONV; ++k) {
    int ls = l - (DCONV - 1) + k;
    if (ls >= 0)
      acc = fmaf(xbc[((size_t)(b * SEQLEN + ls)) * CONVDIM + ch], cw[ch * DCONV + k], acc);
  }
  float s = acc * sigmoidf_(acc);
  if (ch < DINNER)
    xb[(size_t)bl * DINNER + ch] = s;
  else if (ch < DINNER + DSTATE)
    bbuf[(size_t)bl * DSTATE + (ch - DINNER)] = s;
  else
    cbuf[(size_t)bl * DSTATE + (ch - DINNER - DSTATE)] = s;
}

// ---------------------------------------------------------------------------
// dt = softplus(dt_raw + dt_bias); dA = -exp(A_log)*dt   (layout (b*l, h))
// dAb may alias dtraw (element-wise read-then-write).
// ---------------------------------------------------------------------------
__global__ __launch_bounds__(256) void dt_kernel(const float* __restrict__ dtraw,
                                                 const float* __restrict__ dt_bias,
                                                 const float* __restrict__ A_log,
                                                 float* __restrict__ dtv,
                                                 float* dAb) {
  int idx = blockIdx.x * 256 + threadIdx.x;
  if (idx >= BL * NHEADS) return;
  int h = idx & (NHEADS - 1);
  float dtr = dtraw[idx] + dt_bias[h];
  float v = (dtr > 20.f) ? dtr : log1pf(expf(dtr));
  dtv[idx] = v;
  dAb[idx] = -expf(A_log[h]) * v;
}

// ---------------------------------------------------------------------------
// Per (b,c,h): inclusive cumsum of dA over the 256-chunk; also chunk decay.
// ---------------------------------------------------------------------------
__global__ __launch_bounds__(256) void cumsum_kernel(const float* __restrict__ dAb,
                                                     float* __restrict__ acum,
                                                     float* __restrict__ cdec) {
  const int bch = blockIdx.x;              // ((b*NCHUNK+c)*NHEADS+h)
  const int h = bch & (NHEADS - 1);
  const int bc = bch >> 6;
  const int b = bc >> 3, c = bc & (NCHUNK - 1);
  const int s = threadIdx.x;
  __shared__ float buf[CHUNKSZ];
  buf[s] = dAb[((size_t)(b * SEQLEN) + c * CHUNKSZ + s) * NHEADS + h];
  __syncthreads();
  for (int off = 1; off < CHUNKSZ; off <<= 1) {
    float t = (s >= off) ? buf[s - off] : 0.f;
    __syncthreads();
    buf[s] += t;
    __syncthreads();
  }
  float r = buf[s];
  acum[(size_t)bch * CHUNKSZ + s] = r;
  if (s == CHUNKSZ - 1) cdec[bch] = expf(r);
}

// ---------------------------------------------------------------------------
// states[b,c,h,p,n] = sum_s  x[s,p]*dt[s]*exp(aclast-ac[s]) * B[s,n]
// ---------------------------------------------------------------------------
__global__ __launch_bounds__(256) void states_kernel(const float* __restrict__ xb,
                                                     const float* __restrict__ bbuf,
                                                     const float* __restrict__ dtv,
                                                     const float* __restrict__ acum,
                                                     float* __restrict__ states) {
  const int bch = blockIdx.x;
  const int h = bch & (NHEADS - 1);
  const int bc = bch >> 6;
  const int b = bc >> 3, c = bc & (NCHUNK - 1);
  const float* ac = acum + (size_t)bch * CHUNKSZ;
  const float clast = ac[CHUNKSZ - 1];
  __shared__ float xs[32][65];
  __shared__ float bs[32][129];
  __shared__ float wsh[32];
  const int tid = threadIdx.x;
  const int tp = tid >> 4, tn = tid & 15;
  float acc[4][8] = {};
  for (int s0 = 0; s0 < CHUNKSZ; s0 += 32) {
    if (tid < 32) {
      int s = s0 + tid;
      wsh[tid] = expf(clast - ac[s]) *
                 dtv[((size_t)(b * SEQLEN) + c * CHUNKSZ + s) * NHEADS + h];
    }
    __syncthreads();
    for (int e = tid; e < 32 * 64; e += 256) {
      int s = e >> 6, pp = e & 63;
      xs[s][pp] = xb[((size_t)(b * SEQLEN) + c * CHUNKSZ + s0 + s) * DINNER + h * HEADDIM + pp] * wsh[s];
    }
    for (int e = tid; e < 32 * 128; e += 256) {
      int s = e >> 7, n = e & 127;
      bs[s][n] = bbuf[((size_t)(b * SEQLEN) + c * CHUNKSZ + s0 + s) * DSTATE + n];
    }
    __syncthreads();
#pragma unroll 8
    for (int s = 0; s < 32; ++s) {
      float a[4], bv[8];
#pragma unroll
      for (int i = 0; i < 4; ++i) a[i] = xs[s][tp * 4 + i];
#pragma unroll
      for (int j = 0; j < 8; ++j) bv[j] = bs[s][tn * 8 + j];
#pragma unroll
      for (int i = 0; i < 4; ++i)
#pragma unroll
        for (int j = 0; j < 8; ++j)
          acc[i][j] = fmaf(a[i], bv[j], acc[i][j]);
    }
    __syncthreads();
  }
#pragma unroll
  for (int i = 0; i < 4; ++i)
#pragma unroll
    for (int j = 0; j < 8; ++j)
      states[((size_t)bch * HEADDIM + tp * 4 + i) * DSTATE + tn * 8 + j] = acc[i][j];
}

// ---------------------------------------------------------------------------
// Sequential inter-chunk scan, IN-PLACE: st = states[c]; states[c] = S;
// S = cdec[c]*S + st.  After this, `states` holds prev-states.
// ---------------------------------------------------------------------------
__global__ __launch_bounds__(256) void scan_kernel(float* __restrict__ states,
                                                   const float* __restrict__ cdec) {
  int idx = blockIdx.x * 256 + threadIdx.x;     // over B*H*P*N = 1048576
  const int pn = idx & (HEADDIM * DSTATE - 1);
  const int bh = idx >> 13;
  const int h = bh & (NHEADS - 1), b = bh >> 6;
  float S = 0.f;
  for (int c = 0; c < NCHUNK; ++c) {
    int bch = (b * NCHUNK + c) * NHEADS + h;
    size_t off = (size_t)bch * (HEADDIM * DSTATE) + pn;
    float st = states[off];
    states[off] = S;
    S = fmaf(cdec[bch], S, st);
  }
}

// ---------------------------------------------------------------------------
// G0[bc,q,s] = sum_n C[q,n]*B[s,n]  (head-independent, ngroups=1).
// ---------------------------------------------------------------------------
__global__ __launch_bounds__(256) void cb_kernel(const float* __restrict__ cbuf,
                                                 const float* __restrict__ bbuf,
                                                 float* __restrict__ g0) {
  const int qb = blockIdx.x >> 2, sb = blockIdx.x & 3;
  if (sb > qb) return;
  const int bc = blockIdx.y;
  const int tid = threadIdx.x;
  __shared__ float As[16][65];
  __shared__ float Bs[16][65];
  const int lr = tid >> 2, lk = (tid & 3) << 2;
  const int tx = tid & 15, ty = tid >> 4;
  float acc[4][4] = {};
  const float* Arow = cbuf + ((size_t)bc * CHUNKSZ + qb * 64) * DSTATE;
  const float* Brow = bbuf + ((size_t)bc * CHUNKSZ + sb * 64) * DSTATE;
  for (int k0 = 0; k0 < DSTATE; k0 += 16) {
    float4 av = *(const float4*)(Arow + (size_t)lr * DSTATE + k0 + lk);
    float4 bv = *(const float4*)(Brow + (size_t)lr * DSTATE + k0 + lk);
    As[lk + 0][lr] = av.x; As[lk + 1][lr] = av.y; As[lk + 2][lr] = av.z; As[lk + 3][lr] = av.w;
    Bs[lk + 0][lr] = bv.x; Bs[lk + 1][lr] = bv.y; Bs[lk + 2][lr] = bv.z; Bs[lk + 3][lr] = bv.w;
    __syncthreads();
#pragma unroll
    for (int kk = 0; kk < 16; ++kk) {
      float a[4], bv2[4];
#pragma unroll
      for (int i = 0; i < 4; ++i) a[i] = As[kk][ty * 4 + i];
#pragma unroll
      for (int j = 0; j < 4; ++j) bv2[j] = Bs[kk][tx * 4 + j];
#pragma unroll
      for (int i = 0; i < 4; ++i)
#pragma unroll
        for (int j = 0; j < 4; ++j)
          acc[i][j] = fmaf(a[i], bv2[j], acc[i][j]);
    }
    __syncthreads();
  }
#pragma unroll
  for (int i = 0; i < 4; ++i)
#pragma unroll
    for (int j = 0; j < 4; ++j)
      g0[((size_t)bc * CHUNKSZ + qb * 64 + ty * 4 + i) * CHUNKSZ + sb * 64 + tx * 4 + j] = acc[i][j];
}

// ---------------------------------------------------------------------------
// Y[q,p] = sum_{s<=q} G0[q,s]*exp(ac[q]-ac[s])*dt[s] * x[s,p]
//        + exp(ac[q]) * sum_n C[q,n]*prev[p,n]  + D[h]*x[q,p]
// ---------------------------------------------------------------------------
__global__ __launch_bounds__(256) void y_kernel(const float* __restrict__ xb,
                                                const float* __restrict__ cbuf,
                                                const float* __restrict__ g0,
                                                const float* __restrict__ acum,
                                                const float* __restrict__ dtv,
                                                const float* __restrict__ prevb,
                                                const float* __restrict__ Dvec,
                                                float* __restrict__ yb) {
  const int qb = blockIdx.x & 3;
  const int h = (blockIdx.x >> 2) & (NHEADS - 1);
  const int bc = blockIdx.x >> 8;
  const int b = bc >> 3, c = bc & (NCHUNK - 1);
  const int tid = threadIdx.x;
  const int tq = tid >> 4, tp = tid & 15;
  const float* ac = acum + ((size_t)bc * NHEADS + h) * CHUNKSZ;
  __shared__ float gs[64][33];
  __shared__ float xs[32][65];
  __shared__ float ps[64][33];
  const int qbase = qb * 64;
  float acc[4][4] = {};
  // ---- diagonal (intra-chunk) part ----
  for (int s0 = 0; s0 < qbase + 64; s0 += 32) {
    for (int e = tid; e < 64 * 32; e += 256) {
      int q = e >> 5, s = e & 31;
      int gq = qbase + q, gsd = s0 + s;
      float v = 0.f;
      if (gsd <= gq) {
        float lw = expf(ac[gq] - ac[gsd]);
        float dv = dtv[((size_t)(b * SEQLEN) + c * CHUNKSZ + gsd) * NHEADS + h];
        v = g0[((size_t)bc * CHUNKSZ + gq) * CHUNKSZ + gsd] * lw * dv;
      }
      gs[q][s] = v;
    }
    for (int e = tid; e < 32 * 64; e += 256) {
      int s = e >> 6, pp = e & 63;
      xs[s][pp] = xb[((size_t)(b * SEQLEN) + c * CHUNKSZ + s0 + s) * DINNER + h * HEADDIM + pp];
    }
    __syncthreads();
#pragma unroll 8
    for (int s = 0; s < 32; ++s) {
      float a[4], xv[4];
#pragma unroll
      for (int i = 0; i < 4; ++i) a[i] = gs[tq * 4 + i][s];
#pragma unroll
      for (int j = 0; j < 4; ++j) xv[j] = xs[s][tp * 4 + j];
#pragma unroll
      for (int i = 0; i < 4; ++i)
#pragma unroll
        for (int j = 0; j < 4; ++j)
          acc[i][j] = fmaf(a[i], xv[j], acc[i][j]);
    }
    __syncthreads();
  }
  // ---- off-diagonal (inter-chunk) part: C . prev^T ----
  float acc2[4][4] = {};
  for (int n0 = 0; n0 < DSTATE; n0 += 32) {
    for (int e = tid; e < 64 * 32; e += 256) {
      int q = e >> 5, n = e & 31;
      gs[q][n] = cbuf[((size_t)(b * SEQLEN) + c * CHUNKSZ + qbase + q) * DSTATE + n0 + n];
    }
    for (int e = tid; e < 64 * 32; e += 256) {
      int pp = e >> 5, n = e & 31;
      ps[pp][n] = prevb[(((size_t)bc * NHEADS + h) * HEADDIM + pp) * DSTATE + n0 + n];
    }
    __syncthreads();
#pragma unroll 8
    for (int n = 0; n < 32; ++n) {
      float a[4], pv[4];
#pragma unroll
      for (int i = 0; i < 4; ++i) a[i] = gs[tq * 4 + i][n];
#pragma unroll
      for (int j = 0; j < 4; ++j) pv[j] = ps[tp * 4 + j][n];
#pragma unroll
      for (int i = 0; i < 4; ++i)
#pragma unroll
        for (int j = 0; j < 4; ++j)
          acc2[i][j] = fmaf(a[i], pv[j], acc2[i][j]);
    }
    __syncthreads();
  }
  // ---- epilogue ----
  const float dh = Dvec[h];
#pragma unroll
  for (int i = 0; i < 4; ++i) {
    int q = qbase + tq * 4 + i;
    float eaq = expf(ac[q]);
    size_t row = ((size_t)(b * SEQLEN) + c * CHUNKSZ + q) * DINNER + h * HEADDIM;
#pragma unroll
    for (int j = 0; j < 4; ++j) {
      int pp = tp * 4 + j;
      float xv = xb[row + pp];
      yb[row + pp] = acc[i][j] + eaq * acc2[i][j] + dh * xv;
    }
  }
}

// ---------------------------------------------------------------------------
// y = y*silu(z); y *= rsqrt(mean(y^2)+eps)*norm_w    one block per (b,l) row
// ---------------------------------------------------------------------------
__global__ __launch_bounds__(256) void norm_kernel(const float* __restrict__ yb,
                                                   const float* __restrict__ zbuf,
                                                   const float* __restrict__ nw,
                                                   float* __restrict__ yo) {
  const int bl = blockIdx.x;
  const float* y = yb + (size_t)bl * DINNER;
  const float* z = zbuf + (size_t)bl * DINNER;
  float vals[16];
  float ss = 0.f;
  int j = 0;
  for (int i = threadIdx.x; i < DINNER; i += 256, ++j) {
    float zz = z[i];
    float g = y[i] * zz * sigmoidf_(zz);
    vals[j] = g;
    ss = fmaf(g, g, ss);
  }
  for (int off = 32; off > 0; off >>= 1) ss += __shfl_down(ss, off, 64);
  __shared__ float red[4];
  if ((threadIdx.x & 63) == 0) red[threadIdx.x >> 6] = ss;
  __syncthreads();
  float tot = red[0] + red[1] + red[2] + red[3];
  float scale = rsqrtf(tot * (1.f / DINNER) + EPSV);
  j = 0;
  for (int i = threadIdx.x; i < DINNER; i += 256, ++j)
    yo[(size_t)bl * DINNER + i] = vals[j] * scale * nw[i];
}

// ---------------------------------------------------------------------------
extern "C" void kernel_launch(void* const* d_in, const int* in_sizes, int n_in,
                              void* d_out, int out_size, void* d_ws, size_t ws_size,
                              hipStream_t stream) {
  const float* u        = (const float*)d_in[0];
  const float* Wp       = (const float*)d_in[1];
  const float* conv_w   = (const float*)d_in[2];
  const float* conv_b   = (const float*)d_in[3];
  const float* dt_bias  = (const float*)d_in[4];
  const float* A_log    = (const float*)d_in[5];
  const float* Dvec     = (const float*)d_in[6];
  const float* norm_w   = (const float*)d_in[7];
  const float* Wo       = (const float*)d_in[8];
  float* out = (float*)d_out;

  char* p = (char*)d_ws;
  auto alloc = [&](size_t nfloats) {
    float* r = (float*)p;
    p += nfloats * sizeof(float);
    return r;
  };
  // static ws total ~213 MB
  float* zbuf   = alloc((size_t)BL * DINNER);                        // 67 MB
  float* xbc    = alloc((size_t)BL * CONVDIM);                       // 71.3 MB
  float* dtraw  = alloc((size_t)BL * NHEADS);                        // 1 MB
  float* xb     = alloc((size_t)BL * DINNER);                        // 67 MB
  float* bbuf   = alloc((size_t)BL * DSTATE);                        // 2 MB
  float* cbuf   = alloc((size_t)BL * DSTATE);                        // 2 MB
  float* dtvb   = alloc((size_t)BL * NHEADS);                        // 1 MB
  float* acum   = alloc((size_t)BATCH * NCHUNK * NHEADS * CHUNKSZ);  // 1 MB
  float* cdec   = alloc((size_t)BATCH * NCHUNK * NHEADS);            // 4 KB
  // overlays (no extra ws):
  float* dAb    = dtraw;              // dt_kernel reads dtraw[i] before writing dAb[i]
  float* states = out;                // d_out (33.5 MB) == exact size of states; dead before step 10
  float* g0     = xbc + (size_t)BL * DINNER;  // 4.19 MB tail slack of xbc (yb uses only BL*DINNER)
  float* yb     = xbc;                // xbc dead after conv_silu_split
  float* yo     = xb;                 // xb dead after y_kernel

  // 1. in_proj GEMM (split outputs)
  gemm_inproj<<<dim3((DINPROJ + 127) / 128, BL / 128), 256, 0, stream>>>(u, Wp, zbuf, xbc, dtraw);
  // 2. conv + silu + split
  conv_silu_split<<<(BL * CONVDIM + 255) / 256, 256, 0, stream>>>(xbc, conv_w, conv_b, xb, bbuf, cbuf);
  // 3. dt softplus + dA  (dAb aliases dtraw)
  dt_kernel<<<(BL * NHEADS + 255) / 256, 256, 0, stream>>>(dtraw, dt_bias, A_log, dtvb, dAb);
  // 4. per-chunk cumsum of dA
  cumsum_kernel<<<BATCH * NCHUNK * NHEADS, CHUNKSZ, 0, stream>>>(dAb, acum, cdec);
  // 5. chunk states (states lives in d_out)
  states_kernel<<<BATCH * NCHUNK * NHEADS, 256, 0, stream>>>(xb, bbuf, dtvb, acum, states);
  // 6. inter-chunk scan (in place: states becomes prev-states)
  scan_kernel<<<(BATCH * NHEADS * HEADDIM * DSTATE) / 256, 256, 0, stream>>>(states, cdec);
  // 7. G0 = C.B^T (shared across heads; g0 in xbc tail slack)
  cb_kernel<<<dim3(16, BATCH * NCHUNK), 256, 0, stream>>>(cbuf, bbuf, g0);
  // 8. Y = diag + off + D*x   (yb aliases xbc head; disjoint from g0 tail)
  y_kernel<<<BATCH * NCHUNK * NHEADS * 4, 256, 0, stream>>>(xb, cbuf, g0, acum, dtvb, states, Dvec, yb);
  // 9. gated RMSNorm (yo aliases xb)
  norm_kernel<<<BL, 256, 0, stream>>>(yb, zbuf, norm_w, yo);
  // 10. out_proj GEMM (overwrites d_out after states is dead)
  gemm_bt128<<<dim3(DMODEL / 128, BL / 128), 256, 0, stream>>>(yo, Wo, out, BL, DMODEL, DINNER);
}

// Round 9
// 1734.670 us; speedup vs baseline: 2.0768x; 2.0768x over previous
//
#include <hip/hip_runtime.h>
#include <cstddef>
#include <cstdint>

#define BATCH   2
#define SEQLEN  2048
#define DMODEL  2048
#define DINNER  4096
#define NHEADS  64
#define HEADDIM 64
#define DSTATE  128
#define DCONV   4
#define CHUNKSZ 256
#define NCHUNK  (SEQLEN / CHUNKSZ)                 // 8
#define CONVDIM (DINNER + 2 * DSTATE)              // 4352
#define DINPROJ (2 * DINNER + 2 * DSTATE + NHEADS) // 8512
#define BL      (BATCH * SEQLEN)                   // 4096
#define EPSV    1e-5f

typedef __attribute__((ext_vector_type(8))) short short8v;
typedef __attribute__((ext_vector_type(4))) float floatx4;

__device__ __forceinline__ float sigmoidf_(float x) { return 1.f / (1.f + expf(-x)); }

__device__ __forceinline__ unsigned short f2bf(float x) {
  uint32_t u = __float_as_uint(x);
  uint32_t r = (u + 0x7FFFu + ((u >> 16) & 1u)) >> 16;
  return (unsigned short)r;
}
__device__ __forceinline__ float bf2f(unsigned short h) {
  return __uint_as_float(((uint32_t)h) << 16);
}

__device__ __forceinline__ void gload16(const void* g, void* l) {
  __builtin_amdgcn_global_load_lds((const __attribute__((address_space(1))) void*)g,
                                   (__attribute__((address_space(3))) void*)l, 16, 0, 0);
}

// ---------------------------------------------------------------------------
// Split fp32 -> (bf16 hi, bf16 lo), 4 elements per thread.
// ---------------------------------------------------------------------------
__global__ __launch_bounds__(256) void split4_kernel(const float* __restrict__ x,
                                                     unsigned short* __restrict__ hi,
                                                     unsigned short* __restrict__ lo,
                                                     int n4) {
  int i = blockIdx.x * 256 + threadIdx.x;
  if (i >= n4) return;
  float4 v = ((const float4*)x)[i];
  ushort4 hv, lv;
  hv.x = f2bf(v.x); lv.x = f2bf(v.x - bf2f(hv.x));
  hv.y = f2bf(v.y); lv.y = f2bf(v.y - bf2f(hv.y));
  hv.z = f2bf(v.z); lv.z = f2bf(v.z - bf2f(hv.z));
  hv.w = f2bf(v.w); lv.w = f2bf(v.w - bf2f(hv.w));
  ((ushort4*)hi)[i] = hv;
  ((ushort4*)lo)[i] = lv;
}

// ---------------------------------------------------------------------------
// Split-bf16 3-term MFMA GEMM: C[M,N] = (Ah+Al)[M,K] * (Bh+Bl)[N,K]^T
// (term Al*Bl omitted, ~2^-16 relative). 128x128 tile, K-step 32, 256 thr
// = 4 waves in 2x2 of 64x64; each wave 4x4 frags of mfma_f32_16x16x32_bf16.
// lda/ldb in bf16 elements. EPI=0: store o0[M,N]. EPI=1: in_proj split
// (cols [0,4096)->o0 zbuf, [4096,8448)->o1 xbc, [8448,8512)->o2 dtraw).
// Staging: global_load_lds width-16 into linear LDS [arr][kg][128][8].
// ---------------------------------------------------------------------------
template <int EPI>
__global__ __launch_bounds__(256) void gemm3bf(const unsigned short* __restrict__ Ah,
                                               const unsigned short* __restrict__ Al, int lda,
                                               const unsigned short* __restrict__ Bh,
                                               const unsigned short* __restrict__ Bl, int ldb,
                                               int M, int N, int K,
                                               float* __restrict__ o0, float* __restrict__ o1,
                                               float* __restrict__ o2) {
  __shared__ __align__(16) unsigned short lds[4][4][128][8];  // 32 KB
  const int tid = threadIdx.x;
  const int lane = tid & 63;
  const int w = tid >> 6, wm = w >> 1, wn = w & 1;
  const int bm = blockIdx.y * 128, bn = blockIdx.x * 128;
  const int r16 = lane & 15, kg = lane >> 4;
  floatx4 acc[4][4] = {};

  for (int k0 = 0; k0 < K; k0 += 32) {
#pragma unroll
    for (int arr = 0; arr < 4; ++arr) {
      const unsigned short* src = (arr == 0) ? Ah : (arr == 1) ? Al : (arr == 2) ? Bh : Bl;
      const int ld = (arr < 2) ? lda : ldb;
#pragma unroll
      for (int t = 0; t < 2; ++t) {
        int ubase = t * 256 + w * 64;  // wave-uniform
        int u = ubase + lane;
        int g = u >> 7, m = u & 127;
        int row;
        if (arr < 2) row = bm + m;               // M is a multiple of 128
        else { row = bn + m; if (row >= N) row = N - 1; }
        const unsigned short* gp = src + (size_t)row * ld + k0 + g * 8;
        gload16(gp, (void*)(&lds[arr][0][0][0] + (size_t)ubase * 8));
      }
    }
    __syncthreads();

    short8v bhf[4], blf[4];
#pragma unroll
    for (int j = 0; j < 4; ++j) {
      int n_in = wn * 64 + j * 16 + r16;
      bhf[j] = *(const short8v*)&lds[2][kg][n_in][0];
      blf[j] = *(const short8v*)&lds[3][kg][n_in][0];
    }
#pragma unroll
    for (int i = 0; i < 4; ++i) {
      int m_in = wm * 64 + i * 16 + r16;
      short8v ah = *(const short8v*)&lds[0][kg][m_in][0];
      short8v al = *(const short8v*)&lds[1][kg][m_in][0];
#pragma unroll
      for (int j = 0; j < 4; ++j) {
        acc[i][j] = __builtin_amdgcn_mfma_f32_16x16x32_bf16(ah, bhf[j], acc[i][j], 0, 0, 0);
        acc[i][j] = __builtin_amdgcn_mfma_f32_16x16x32_bf16(ah, blf[j], acc[i][j], 0, 0, 0);
        acc[i][j] = __builtin_amdgcn_mfma_f32_16x16x32_bf16(al, bhf[j], acc[i][j], 0, 0, 0);
      }
    }
    __syncthreads();
  }

  // C/D layout (m89-verified): n = lane&15, m = (lane>>4)*4 + reg
#pragma unroll
  for (int i = 0; i < 4; ++i) {
#pragma unroll
    for (int j = 0; j < 4; ++j) {
      int n = bn + wn * 64 + j * 16 + r16;
#pragma unroll
      for (int r = 0; r < 4; ++r) {
        int m = bm + wm * 64 + i * 16 + kg * 4 + r;
        float v = acc[i][j][r];
        if (EPI == 0) {
          o0[(size_t)m * N + n] = v;
        } else {
          if (n < DINNER) o0[(size_t)m * DINNER + n] = v;
          else if (n < DINNER + CONVDIM) o1[(size_t)m * CONVDIM + (n - DINNER)] = v;
          else if (n < DINPROJ) o2[(size_t)m * NHEADS + (n - DINNER - CONVDIM)] = v;
        }
      }
    }
  }
}

// ---------------------------------------------------------------------------
// Causal depthwise conv (k=4) + SiLU + split into x / B / C
// ---------------------------------------------------------------------------
__global__ __launch_bounds__(256) void conv_silu_split(const float* __restrict__ xbc,
                                                       const float* __restrict__ cw,
                                                       const float* __restrict__ cb,
                                                       float* __restrict__ xb,
                                                       float* __restrict__ bbuf,
                                                       float* __restrict__ cbuf) {
  int idx = blockIdx.x * 256 + threadIdx.x;
  if (idx >= BL * CONVDIM) return;
  int ch = idx % CONVDIM;
  int bl = idx / CONVDIM;
  int l = bl & (SEQLEN - 1);
  int b = bl / SEQLEN;
  float acc = cb[ch];
#pragma unroll
  for (int k = 0; k < DCONV; ++k) {
    int ls = l - (DCONV - 1) + k;
    if (ls >= 0)
      acc = fmaf(xbc[((size_t)(b * SEQLEN + ls)) * CONVDIM + ch], cw[ch * DCONV + k], acc);
  }
  float s = acc * sigmoidf_(acc);
  if (ch < DINNER)
    xb[(size_t)bl * DINNER + ch] = s;
  else if (ch < DINNER + DSTATE)
    bbuf[(size_t)bl * DSTATE + (ch - DINNER)] = s;
  else
    cbuf[(size_t)bl * DSTATE + (ch - DINNER - DSTATE)] = s;
}

// ---------------------------------------------------------------------------
// dt = softplus(dt_raw + dt_bias); dA = -exp(A_log)*dt   (layout (b*l, h))
// ---------------------------------------------------------------------------
__global__ __launch_bounds__(256) void dt_kernel(const float* __restrict__ dtraw,
                                                 const float* __restrict__ dt_bias,
                                                 const float* __restrict__ A_log,
                                                 float* __restrict__ dtv,
                                                 float* dAb) {
  int idx = blockIdx.x * 256 + threadIdx.x;
  if (idx >= BL * NHEADS) return;
  int h = idx & (NHEADS - 1);
  float dtr = dtraw[idx] + dt_bias[h];
  float v = (dtr > 20.f) ? dtr : log1pf(expf(dtr));
  dtv[idx] = v;
  dAb[idx] = -expf(A_log[h]) * v;
}

// ---------------------------------------------------------------------------
// Per (b,c,h): inclusive cumsum of dA over the 256-chunk; also chunk decay.
// ---------------------------------------------------------------------------
__global__ __launch_bounds__(256) void cumsum_kernel(const float* __restrict__ dAb,
                                                     float* __restrict__ acum,
                                                     float* __restrict__ cdec) {
  const int bch = blockIdx.x;
  const int h = bch & (NHEADS - 1);
  const int bc = bch >> 6;
  const int b = bc >> 3, c = bc & (NCHUNK - 1);
  const int s = threadIdx.x;
  __shared__ float buf[CHUNKSZ];
  buf[s] = dAb[((size_t)(b * SEQLEN) + c * CHUNKSZ + s) * NHEADS + h];
  __syncthreads();
  for (int off = 1; off < CHUNKSZ; off <<= 1) {
    float t = (s >= off) ? buf[s - off] : 0.f;
    __syncthreads();
    buf[s] += t;
    __syncthreads();
  }
  float r = buf[s];
  acum[(size_t)bch * CHUNKSZ + s] = r;
  if (s == CHUNKSZ - 1) cdec[bch] = expf(r);
}

// ---------------------------------------------------------------------------
// states[b,c,h,p,n] = sum_s  x[s,p]*dt[s]*exp(aclast-ac[s]) * B[s,n]
// ---------------------------------------------------------------------------
__global__ __launch_bounds__(256) void states_kernel(const float* __restrict__ xb,
                                                     const float* __restrict__ bbuf,
                                                     const float* __restrict__ dtv,
                                                     const float* __restrict__ acum,
                                                     float* __restrict__ states) {
  const int bch = blockIdx.x;
  const int h = bch & (NHEADS - 1);
  const int bc = bch >> 6;
  const int b = bc >> 3, c = bc & (NCHUNK - 1);
  const float* ac = acum + (size_t)bch * CHUNKSZ;
  const float clast = ac[CHUNKSZ - 1];
  __shared__ float xs[32][65];
  __shared__ float bs[32][129];
  __shared__ float wsh[32];
  const int tid = threadIdx.x;
  const int tp = tid >> 4, tn = tid & 15;
  float acc[4][8] = {};
  for (int s0 = 0; s0 < CHUNKSZ; s0 += 32) {
    if (tid < 32) {
      int s = s0 + tid;
      wsh[tid] = expf(clast - ac[s]) *
                 dtv[((size_t)(b * SEQLEN) + c * CHUNKSZ + s) * NHEADS + h];
    }
    __syncthreads();
    for (int e = tid; e < 32 * 64; e += 256) {
      int s = e >> 6, pp = e & 63;
      xs[s][pp] = xb[((size_t)(b * SEQLEN) + c * CHUNKSZ + s0 + s) * DINNER + h * HEADDIM + pp] * wsh[s];
    }
    for (int e = tid; e < 32 * 128; e += 256) {
      int s = e >> 7, n = e & 127;
      bs[s][n] = bbuf[((size_t)(b * SEQLEN) + c * CHUNKSZ + s0 + s) * DSTATE + n];
    }
    __syncthreads();
#pragma unroll 8
    for (int s = 0; s < 32; ++s) {
      float a[4], bv[8];
#pragma unroll
      for (int i = 0; i < 4; ++i) a[i] = xs[s][tp * 4 + i];
#pragma unroll
      for (int j = 0; j < 8; ++j) bv[j] = bs[s][tn * 8 + j];
#pragma unroll
      for (int i = 0; i < 4; ++i)
#pragma unroll
        for (int j = 0; j < 8; ++j)
          acc[i][j] = fmaf(a[i], bv[j], acc[i][j]);
    }
    __syncthreads();
  }
#pragma unroll
  for (int i = 0; i < 4; ++i)
#pragma unroll
    for (int j = 0; j < 8; ++j)
      states[((size_t)bch * HEADDIM + tp * 4 + i) * DSTATE + tn * 8 + j] = acc[i][j];
}

// ---------------------------------------------------------------------------
// Sequential inter-chunk scan, IN-PLACE.
// ---------------------------------------------------------------------------
__global__ __launch_bounds__(256) void scan_kernel(float* __restrict__ states,
                                                   const float* __restrict__ cdec) {
  int idx = blockIdx.x * 256 + threadIdx.x;
  const int pn = idx & (HEADDIM * DSTATE - 1);
  const int bh = idx >> 13;
  const int h = bh & (NHEADS - 1), b = bh >> 6;
  float S = 0.f;
  for (int c = 0; c < NCHUNK; ++c) {
    int bch = (b * NCHUNK + c) * NHEADS + h;
    size_t off = (size_t)bch * (HEADDIM * DSTATE) + pn;
    float st = states[off];
    states[off] = S;
    S = fmaf(cdec[bch], S, st);
  }
}

// ---------------------------------------------------------------------------
// G0[bc,q,s] = sum_n C[q,n]*B[s,n]  (head-independent, ngroups=1).
// ---------------------------------------------------------------------------
__global__ __launch_bounds__(256) void cb_kernel(const float* __restrict__ cbuf,
                                                 const float* __restrict__ bbuf,
                                                 float* __restrict__ g0) {
  const int qb = blockIdx.x >> 2, sb = blockIdx.x & 3;
  if (sb > qb) return;
  const int bc = blockIdx.y;
  const int tid = threadIdx.x;
  __shared__ float As[16][65];
  __shared__ float Bs[16][65];
  const int lr = tid >> 2, lk = (tid & 3) << 2;
  const int tx = tid & 15, ty = tid >> 4;
  float acc[4][4] = {};
  const float* Arow = cbuf + ((size_t)bc * CHUNKSZ + qb * 64) * DSTATE;
  const float* Brow = bbuf + ((size_t)bc * CHUNKSZ + sb * 64) * DSTATE;
  for (int k0 = 0; k0 < DSTATE; k0 += 16) {
    float4 av = *(const float4*)(Arow + (size_t)lr * DSTATE + k0 + lk);
    float4 bv = *(const float4*)(Brow + (size_t)lr * DSTATE + k0 + lk);
    As[lk + 0][lr] = av.x; As[lk + 1][lr] = av.y; As[lk + 2][lr] = av.z; As[lk + 3][lr] = av.w;
    Bs[lk + 0][lr] = bv.x; Bs[lk + 1][lr] = bv.y; Bs[lk + 2][lr] = bv.z; Bs[lk + 3][lr] = bv.w;
    __syncthreads();
#pragma unroll
    for (int kk = 0; kk < 16; ++kk) {
      float a[4], bv2[4];
#pragma unroll
      for (int i = 0; i < 4; ++i) a[i] = As[kk][ty * 4 + i];
#pragma unroll
      for (int j = 0; j < 4; ++j) bv2[j] = Bs[kk][tx * 4 + j];
#pragma unroll
      for (int i = 0; i < 4; ++i)
#pragma unroll
        for (int j = 0; j < 4; ++j)
          acc[i][j] = fmaf(a[i], bv2[j], acc[i][j]);
    }
    __syncthreads();
  }
#pragma unroll
  for (int i = 0; i < 4; ++i)
#pragma unroll
    for (int j = 0; j < 4; ++j)
      g0[((size_t)bc * CHUNKSZ + qb * 64 + ty * 4 + i) * CHUNKSZ + sb * 64 + tx * 4 + j] = acc[i][j];
}

// ---------------------------------------------------------------------------
// Y[q,p] = diag + off + D*x
// ---------------------------------------------------------------------------
__global__ __launch_bounds__(256) void y_kernel(const float* __restrict__ xb,
                                                const float* __restrict__ cbuf,
                                                const float* __restrict__ g0,
                                                const float* __restrict__ acum,
                                                const float* __restrict__ dtv,
                                                const float* __restrict__ prevb,
                                                const float* __restrict__ Dvec,
                                                float* __restrict__ yb) {
  const int qb = blockIdx.x & 3;
  const int h = (blockIdx.x >> 2) & (NHEADS - 1);
  const int bc = blockIdx.x >> 8;
  const int b = bc >> 3, c = bc & (NCHUNK - 1);
  const int tid = threadIdx.x;
  const int tq = tid >> 4, tp = tid & 15;
  const float* ac = acum + ((size_t)bc * NHEADS + h) * CHUNKSZ;
  __shared__ float gs[64][33];
  __shared__ float xs[32][65];
  __shared__ float ps[64][33];
  const int qbase = qb * 64;
  float acc[4][4] = {};
  for (int s0 = 0; s0 < qbase + 64; s0 += 32) {
    for (int e = tid; e < 64 * 32; e += 256) {
      int q = e >> 5, s = e & 31;
      int gq = qbase + q, gsd = s0 + s;
      float v = 0.f;
      if (gsd <= gq) {
        float lw = expf(ac[gq] - ac[gsd]);
        float dv = dtv[((size_t)(b * SEQLEN) + c * CHUNKSZ + gsd) * NHEADS + h];
        v = g0[((size_t)bc * CHUNKSZ + gq) * CHUNKSZ + gsd] * lw * dv;
      }
      gs[q][s] = v;
    }
    for (int e = tid; e < 32 * 64; e += 256) {
      int s = e >> 6, pp = e & 63;
      xs[s][pp] = xb[((size_t)(b * SEQLEN) + c * CHUNKSZ + s0 + s) * DINNER + h * HEADDIM + pp];
    }
    __syncthreads();
#pragma unroll 8
    for (int s = 0; s < 32; ++s) {
      float a[4], xv[4];
#pragma unroll
      for (int i = 0; i < 4; ++i) a[i] = gs[tq * 4 + i][s];
#pragma unroll
      for (int j = 0; j < 4; ++j) xv[j] = xs[s][tp * 4 + j];
#pragma unroll
      for (int i = 0; i < 4; ++i)
#pragma unroll
        for (int j = 0; j < 4; ++j)
          acc[i][j] = fmaf(a[i], xv[j], acc[i][j]);
    }
    __syncthreads();
  }
  float acc2[4][4] = {};
  for (int n0 = 0; n0 < DSTATE; n0 += 32) {
    for (int e = tid; e < 64 * 32; e += 256) {
      int q = e >> 5, n = e & 31;
      gs[q][n] = cbuf[((size_t)(b * SEQLEN) + c * CHUNKSZ + qbase + q) * DSTATE + n0 + n];
    }
    for (int e = tid; e < 64 * 32; e += 256) {
      int pp = e >> 5, n = e & 31;
      ps[pp][n] = prevb[(((size_t)bc * NHEADS + h) * HEADDIM + pp) * DSTATE + n0 + n];
    }
    __syncthreads();
#pragma unroll 8
    for (int n = 0; n < 32; ++n) {
      float a[4], pv[4];
#pragma unroll
      for (int i = 0; i < 4; ++i) a[i] = gs[tq * 4 + i][n];
#pragma unroll
      for (int j = 0; j < 4; ++j) pv[j] = ps[tp * 4 + j][n];
#pragma unroll
      for (int i = 0; i < 4; ++i)
#pragma unroll
        for (int j = 0; j < 4; ++j)
          acc2[i][j] = fmaf(a[i], pv[j], acc2[i][j]);
    }
    __syncthreads();
  }
  const float dh = Dvec[h];
#pragma unroll
  for (int i = 0; i < 4; ++i) {
    int q = qbase + tq * 4 + i;
    float eaq = expf(ac[q]);
    size_t row = ((size_t)(b * SEQLEN) + c * CHUNKSZ + q) * DINNER + h * HEADDIM;
#pragma unroll
    for (int j = 0; j < 4; ++j) {
      int pp = tp * 4 + j;
      float xv = xb[row + pp];
      yb[row + pp] = acc[i][j] + eaq * acc2[i][j] + dh * xv;
    }
  }
}

// ---------------------------------------------------------------------------
// gated RMSNorm; writes bf16 hi/lo split IN-PLACE over yb's row
// (row read fully before the reduction barrier; writes after it).
// ---------------------------------------------------------------------------
__global__ __launch_bounds__(256) void norm_kernel(float* yb,
                                                   const float* __restrict__ zbuf,
                                                   const float* __restrict__ nw) {
  const int bl = blockIdx.x;
  float* y = yb + (size_t)bl * DINNER;
  const float* z = zbuf + (size_t)bl * DINNER;
  float vals[16];
  float ss = 0.f;
  int j = 0;
  for (int i = threadIdx.x; i < DINNER; i += 256, ++j) {
    float zz = z[i];
    float g = y[i] * zz * sigmoidf_(zz);
    vals[j] = g;
    ss = fmaf(g, g, ss);
  }
  for (int off = 32; off > 0; off >>= 1) ss += __shfl_down(ss, off, 64);
  __shared__ float red[4];
  if ((threadIdx.x & 63) == 0) red[threadIdx.x >> 6] = ss;
  __syncthreads();
  float tot = red[0] + red[1] + red[2] + red[3];
  float scale = rsqrtf(tot * (1.f / DINNER) + EPSV);
  unsigned short* yh = (unsigned short*)y;   // 4096 ushorts = first 2048 floats
  unsigned short* yl = yh + DINNER;          // next 2048 floats
  j = 0;
  for (int i = threadIdx.x; i < DINNER; i += 256, ++j) {
    float v = vals[j] * scale * nw[i];
    unsigned short h = f2bf(v);
    yh[i] = h;
    yl[i] = f2bf(v - bf2f(h));
  }
}

// ---------------------------------------------------------------------------
extern "C" void kernel_launch(void* const* d_in, const int* in_sizes, int n_in,
                              void* d_out, int out_size, void* d_ws, size_t ws_size,
                              hipStream_t stream) {
  const float* u        = (const float*)d_in[0];
  const float* Wp       = (const float*)d_in[1];
  const float* conv_w   = (const float*)d_in[2];
  const float* conv_b   = (const float*)d_in[3];
  const float* dt_bias  = (const float*)d_in[4];
  const float* A_log    = (const float*)d_in[5];
  const float* Dvec     = (const float*)d_in[6];
  const float* norm_w   = (const float*)d_in[7];
  const float* Wo       = (const float*)d_in[8];
  float* out = (float*)d_out;

  char* p = (char*)d_ws;
  auto alloc = [&](size_t nfloats) {
    float* r = (float*)p;
    p += nfloats * sizeof(float);
    return r;
  };
  // static ws total ~213 MB (same as passing r7)
  float* zbuf   = alloc((size_t)BL * DINNER);                        // 67 MB
  float* xbc    = alloc((size_t)BL * CONVDIM);                       // 71.3 MB
  float* dtraw  = alloc((size_t)BL * NHEADS);                        // 1 MB
  float* xb     = alloc((size_t)BL * DINNER);                        // 67 MB
  float* bbuf   = alloc((size_t)BL * DSTATE);                        // 2 MB
  float* cbuf   = alloc((size_t)BL * DSTATE);                        // 2 MB
  float* dtvb   = alloc((size_t)BL * NHEADS);                        // 1 MB
  float* acum   = alloc((size_t)BATCH * NCHUNK * NHEADS * CHUNKSZ);  // 1 MB
  float* cdec   = alloc((size_t)BATCH * NCHUNK * NHEADS);            // 4 KB
  // overlays (no extra ws):
  float* dAb    = dtraw;                       // elementwise read-then-write
  float* states = out;                         // exact size; dead before step 10
  float* g0     = xbc + (size_t)BL * DINNER;   // xbc tail slack
  float* yb     = xbc;                         // xbc dead after conv
  // bf16 split overlays:
  unsigned short* u_hi  = (unsigned short*)d_out;                 // dead before states
  unsigned short* u_lo  = u_hi + (size_t)BL * DMODEL;             // exactly fills d_out
  unsigned short* wp_hi = (unsigned short*)xb;                    // xb/bbuf/cbuf dead until step 2
  unsigned short* wp_lo = wp_hi + (size_t)DINPROJ * DMODEL;       // 66.5 MiB across xb+bbuf+cbuf
  unsigned short* wo_hi = (unsigned short*)zbuf;                  // zbuf dead after norm
  unsigned short* wo_lo = wo_hi + (size_t)DMODEL * DINNER;
  unsigned short* yo_hi = (unsigned short*)xbc;                   // per-row in-place split
  unsigned short* yo_lo = yo_hi + DINNER;                         // row stride 2*DINNER ushorts

  // 0a. split u -> bf16 hi/lo (in d_out)
  split4_kernel<<<(BL * DMODEL / 4 + 255) / 256, 256, 0, stream>>>(u, u_hi, u_lo, BL * DMODEL / 4);
  // 0b. split Wp -> bf16 hi/lo (in xb region)
  split4_kernel<<<(DINPROJ * DMODEL / 4 + 255) / 256, 256, 0, stream>>>(Wp, wp_hi, wp_lo,
                                                                        DINPROJ * DMODEL / 4);
  // 1. in_proj MFMA GEMM (split epilogue)
  gemm3bf<1><<<dim3((DINPROJ + 127) / 128, BL / 128), 256, 0, stream>>>(
      u_hi, u_lo, DMODEL, wp_hi, wp_lo, DMODEL, BL, DINPROJ, DMODEL, zbuf, xbc, dtraw);
  // 2. conv + silu + split
  conv_silu_split<<<(BL * CONVDIM + 255) / 256, 256, 0, stream>>>(xbc, conv_w, conv_b, xb, bbuf, cbuf);
  // 3. dt softplus + dA  (dAb aliases dtraw)
  dt_kernel<<<(BL * NHEADS + 255) / 256, 256, 0, stream>>>(dtraw, dt_bias, A_log, dtvb, dAb);
  // 4. per-chunk cumsum of dA
  cumsum_kernel<<<BATCH * NCHUNK * NHEADS, CHUNKSZ, 0, stream>>>(dAb, acum, cdec);
  // 5. chunk states (in d_out)
  states_kernel<<<BATCH * NCHUNK * NHEADS, 256, 0, stream>>>(xb, bbuf, dtvb, acum, states);
  // 6. inter-chunk scan (in place)
  scan_kernel<<<(BATCH * NHEADS * HEADDIM * DSTATE) / 256, 256, 0, stream>>>(states, cdec);
  // 7. G0 = C.B^T
  cb_kernel<<<dim3(16, BATCH * NCHUNK), 256, 0, stream>>>(cbuf, bbuf, g0);
  // 8. Y = diag + off + D*x
  y_kernel<<<BATCH * NCHUNK * NHEADS * 4, 256, 0, stream>>>(xb, cbuf, g0, acum, dtvb, states, Dvec, yb);
  // 9. gated RMSNorm -> bf16 hi/lo in place over yb rows
  norm_kernel<<<BL, 256, 0, stream>>>(yb, zbuf, norm_w);
  // 9b. split Wo -> bf16 hi/lo (in zbuf region, dead after norm)
  split4_kernel<<<(DMODEL * DINNER / 4 + 255) / 256, 256, 0, stream>>>(Wo, wo_hi, wo_lo,
                                                                      DMODEL * DINNER / 4);
  // 10. out_proj MFMA GEMM -> d_out (states dead)
  gemm3bf<0><<<dim3(DMODEL / 128, BL / 128), 256, 0, stream>>>(
      yo_hi, yo_lo, 2 * DINNER, wo_hi, wo_lo, DINNER, BL, DMODEL, DINNER, out, nullptr, nullptr);
}

// Round 10
// 1677.994 us; speedup vs baseline: 2.1469x; 1.0338x over previous
//
#include <hip/hip_runtime.h>
#include <cstddef>
#include <cstdint>

#define BATCH   2
#define SEQLEN  2048
#define DMODEL  2048
#define DINNER  4096
#define NHEADS  64
#define HEADDIM 64
#define DSTATE  128
#define DCONV   4
#define CHUNKSZ 256
#define NCHUNK  (SEQLEN / CHUNKSZ)                 // 8
#define CONVDIM (DINNER + 2 * DSTATE)              // 4352
#define DINPROJ (2 * DINNER + 2 * DSTATE + NHEADS) // 8512
#define BL      (BATCH * SEQLEN)                   // 4096
#define EPSV    1e-5f

typedef __attribute__((ext_vector_type(8))) short short8v;
typedef __attribute__((ext_vector_type(4))) float floatx4;

__device__ __forceinline__ float sigmoidf_(float x) { return 1.f / (1.f + expf(-x)); }

__device__ __forceinline__ unsigned short f2bf(float x) {
  uint32_t u = __float_as_uint(x);
  uint32_t r = (u + 0x7FFFu + ((u >> 16) & 1u)) >> 16;
  return (unsigned short)r;
}
__device__ __forceinline__ float bf2f(unsigned short h) {
  return __uint_as_float(((uint32_t)h) << 16);
}

__device__ __forceinline__ void gload16(const void* g, void* l) {
  __builtin_amdgcn_global_load_lds((const __attribute__((address_space(1))) void*)g,
                                   (__attribute__((address_space(3))) void*)l, 16, 0, 0);
}

// ---------------------------------------------------------------------------
// Split fp32 -> (bf16 hi, bf16 lo), 4 elements per thread.
// ---------------------------------------------------------------------------
__global__ __launch_bounds__(256) void split4_kernel(const float* __restrict__ x,
                                                     unsigned short* __restrict__ hi,
                                                     unsigned short* __restrict__ lo,
                                                     int n4) {
  int i = blockIdx.x * 256 + threadIdx.x;
  if (i >= n4) return;
  float4 v = ((const float4*)x)[i];
  ushort4 hv, lv;
  hv.x = f2bf(v.x); lv.x = f2bf(v.x - bf2f(hv.x));
  hv.y = f2bf(v.y); lv.y = f2bf(v.y - bf2f(hv.y));
  hv.z = f2bf(v.z); lv.z = f2bf(v.z - bf2f(hv.z));
  hv.w = f2bf(v.w); lv.w = f2bf(v.w - bf2f(hv.w));
  ((ushort4*)hi)[i] = hv;
  ((ushort4*)lo)[i] = lv;
}

// ---------------------------------------------------------------------------
// Split-bf16 3-term MFMA GEMM: C[M,N] = (Ah+Al)[M,K] * (Bh+Bl)[N,K]^T
// v2: GROUP_M rasterization + bijective XCD swizzle (L2/L3 B-panel reuse),
// double-buffered LDS 2-phase pipeline (stage t+1 before compute t, one
// barrier/iter), non-temporal epilogue stores (don't evict B panels).
// 128x128 tile, K-step 32, 256 thr = 4 waves (2x2 of 64x64).
// ---------------------------------------------------------------------------
template <int EPI>
__global__ __launch_bounds__(256) void gemm3bf(const unsigned short* __restrict__ Ah,
                                               const unsigned short* __restrict__ Al, int lda,
                                               const unsigned short* __restrict__ Bh,
                                               const unsigned short* __restrict__ Bl, int ldb,
                                               int M, int N, int K,
                                               float* __restrict__ o0, float* __restrict__ o1,
                                               float* __restrict__ o2) {
  __shared__ __align__(16) unsigned short lds[2][4][4][128][8];  // 64 KB (double buffer)
  const int tid = threadIdx.x;
  const int lane = tid & 63;
  const int w = tid >> 6, wm = w >> 1, wn = w & 1;
  const int r16 = lane & 15, kg = lane >> 4;

  // ---- swizzled tile coordinates ----
  const int nbm = M >> 7;               // M multiple of 128
  const int nbn = (N + 127) >> 7;
  const int nblk = nbm * nbn;
  int wgid = blockIdx.x;
  if ((nblk & 7) == 0) {                // bijective XCD chunking (our grids: 2144, 512)
    int q = nblk >> 3;
    wgid = (wgid & 7) * q + (wgid >> 3);
  }
  const int GM = 8;                     // M-rows per raster group
  const int per_group = GM * nbn;
  const int group = wgid / per_group;
  const int gm0 = group * GM;
  int rows = nbm - gm0; if (rows > GM) rows = GM;
  const int rem = wgid - group * per_group;
  const int pm = gm0 + rem % rows;
  const int pn = rem / rows;
  const int bm = pm * 128, bn = pn * 128;

  floatx4 acc[4][4] = {};

  auto stage = [&](int buf, int k0) {
#pragma unroll
    for (int arr = 0; arr < 4; ++arr) {
      const unsigned short* src = (arr == 0) ? Ah : (arr == 1) ? Al : (arr == 2) ? Bh : Bl;
      const int ld = (arr < 2) ? lda : ldb;
#pragma unroll
      for (int t2 = 0; t2 < 2; ++t2) {
        int ubase = t2 * 256 + w * 64;  // wave-uniform LDS base
        int u = ubase + lane;
        int g = u >> 7, m = u & 127;
        int row;
        if (arr < 2) row = bm + m;
        else { row = bn + m; if (row >= N) row = N - 1; }
        const unsigned short* gp = src + (size_t)row * ld + k0 + g * 8;
        gload16(gp, (void*)(&lds[buf][arr][0][0][0] + (size_t)ubase * 8));
      }
    }
  };

  const int nt = K >> 5;
  stage(0, 0);
  int cur = 0;
  for (int t = 0; t < nt; ++t) {
    __syncthreads();                    // drains vmcnt -> lds[cur] ready; prior LDS reads done
    if (t + 1 < nt) stage(cur ^ 1, (t + 1) << 5);   // prefetch next tile under compute
    short8v bhf[4], blf[4];
#pragma unroll
    for (int j = 0; j < 4; ++j) {
      int n_in = wn * 64 + j * 16 + r16;
      bhf[j] = *(const short8v*)&lds[cur][2][kg][n_in][0];
      blf[j] = *(const short8v*)&lds[cur][3][kg][n_in][0];
    }
#pragma unroll
    for (int i = 0; i < 4; ++i) {
      int m_in = wm * 64 + i * 16 + r16;
      short8v ah = *(const short8v*)&lds[cur][0][kg][m_in][0];
      short8v al = *(const short8v*)&lds[cur][1][kg][m_in][0];
#pragma unroll
      for (int j = 0; j < 4; ++j) {
        acc[i][j] = __builtin_amdgcn_mfma_f32_16x16x32_bf16(ah, bhf[j], acc[i][j], 0, 0, 0);
        acc[i][j] = __builtin_amdgcn_mfma_f32_16x16x32_bf16(ah, blf[j], acc[i][j], 0, 0, 0);
        acc[i][j] = __builtin_amdgcn_mfma_f32_16x16x32_bf16(al, bhf[j], acc[i][j], 0, 0, 0);
      }
    }
    cur ^= 1;
  }

  // C/D layout (m89-verified): n = lane&15, m = (lane>>4)*4 + reg. NT stores.
#pragma unroll
  for (int i = 0; i < 4; ++i) {
#pragma unroll
    for (int j = 0; j < 4; ++j) {
      int n = bn + wn * 64 + j * 16 + r16;
#pragma unroll
      for (int r = 0; r < 4; ++r) {
        int m = bm + wm * 64 + i * 16 + kg * 4 + r;
        float v = acc[i][j][r];
        if (EPI == 0) {
          __builtin_nontemporal_store(v, &o0[(size_t)m * N + n]);
        } else {
          if (n < DINNER)
            __builtin_nontemporal_store(v, &o0[(size_t)m * DINNER + n]);
          else if (n < DINNER + CONVDIM)
            __builtin_nontemporal_store(v, &o1[(size_t)m * CONVDIM + (n - DINNER)]);
          else if (n < DINPROJ)
            __builtin_nontemporal_store(v, &o2[(size_t)m * NHEADS + (n - DINNER - CONVDIM)]);
        }
      }
    }
  }
}

// ---------------------------------------------------------------------------
// Causal depthwise conv (k=4) + SiLU + split into x / B / C
// ---------------------------------------------------------------------------
__global__ __launch_bounds__(256) void conv_silu_split(const float* __restrict__ xbc,
                                                       const float* __restrict__ cw,
                                                       const float* __restrict__ cb,
                                                       float* __restrict__ xb,
                                                       float* __restrict__ bbuf,
                                                       float* __restrict__ cbuf) {
  int idx = blockIdx.x * 256 + threadIdx.x;
  if (idx >= BL * CONVDIM) return;
  int ch = idx % CONVDIM;
  int bl = idx / CONVDIM;
  int l = bl & (SEQLEN - 1);
  int b = bl / SEQLEN;
  float acc = cb[ch];
#pragma unroll
  for (int k = 0; k < DCONV; ++k) {
    int ls = l - (DCONV - 1) + k;
    if (ls >= 0)
      acc = fmaf(xbc[((size_t)(b * SEQLEN + ls)) * CONVDIM + ch], cw[ch * DCONV + k], acc);
  }
  float s = acc * sigmoidf_(acc);
  if (ch < DINNER)
    xb[(size_t)bl * DINNER + ch] = s;
  else if (ch < DINNER + DSTATE)
    bbuf[(size_t)bl * DSTATE + (ch - DINNER)] = s;
  else
    cbuf[(size_t)bl * DSTATE + (ch - DINNER - DSTATE)] = s;
}

// ---------------------------------------------------------------------------
// dt = softplus(dt_raw + dt_bias); dA = -exp(A_log)*dt   (layout (b*l, h))
// ---------------------------------------------------------------------------
__global__ __launch_bounds__(256) void dt_kernel(const float* __restrict__ dtraw,
                                                 const float* __restrict__ dt_bias,
                                                 const float* __restrict__ A_log,
                                                 float* __restrict__ dtv,
                                                 float* dAb) {
  int idx = blockIdx.x * 256 + threadIdx.x;
  if (idx >= BL * NHEADS) return;
  int h = idx & (NHEADS - 1);
  float dtr = dtraw[idx] + dt_bias[h];
  float v = (dtr > 20.f) ? dtr : log1pf(expf(dtr));
  dtv[idx] = v;
  dAb[idx] = -expf(A_log[h]) * v;
}

// ---------------------------------------------------------------------------
// Per (b,c,h): inclusive cumsum of dA over the 256-chunk; also chunk decay.
// ---------------------------------------------------------------------------
__global__ __launch_bounds__(256) void cumsum_kernel(const float* __restrict__ dAb,
                                                     float* __restrict__ acum,
                                                     float* __restrict__ cdec) {
  const int bch = blockIdx.x;
  const int h = bch & (NHEADS - 1);
  const int bc = bch >> 6;
  const int b = bc >> 3, c = bc & (NCHUNK - 1);
  const int s = threadIdx.x;
  __shared__ float buf[CHUNKSZ];
  buf[s] = dAb[((size_t)(b * SEQLEN) + c * CHUNKSZ + s) * NHEADS + h];
  __syncthreads();
  for (int off = 1; off < CHUNKSZ; off <<= 1) {
    float t = (s >= off) ? buf[s - off] : 0.f;
    __syncthreads();
    buf[s] += t;
    __syncthreads();
  }
  float r = buf[s];
  acum[(size_t)bch * CHUNKSZ + s] = r;
  if (s == CHUNKSZ - 1) cdec[bch] = expf(r);
}

// ---------------------------------------------------------------------------
// states[b,c,h,p,n] = sum_s  x[s,p]*dt[s]*exp(aclast-ac[s]) * B[s,n]
// ---------------------------------------------------------------------------
__global__ __launch_bounds__(256) void states_kernel(const float* __restrict__ xb,
                                                     const float* __restrict__ bbuf,
                                                     const float* __restrict__ dtv,
                                                     const float* __restrict__ acum,
                                                     float* __restrict__ states) {
  const int bch = blockIdx.x;
  const int h = bch & (NHEADS - 1);
  const int bc = bch >> 6;
  const int b = bc >> 3, c = bc & (NCHUNK - 1);
  const float* ac = acum + (size_t)bch * CHUNKSZ;
  const float clast = ac[CHUNKSZ - 1];
  __shared__ float xs[32][65];
  __shared__ float bs[32][129];
  __shared__ float wsh[32];
  const int tid = threadIdx.x;
  const int tp = tid >> 4, tn = tid & 15;
  float acc[4][8] = {};
  for (int s0 = 0; s0 < CHUNKSZ; s0 += 32) {
    if (tid < 32) {
      int s = s0 + tid;
      wsh[tid] = expf(clast - ac[s]) *
                 dtv[((size_t)(b * SEQLEN) + c * CHUNKSZ + s) * NHEADS + h];
    }
    __syncthreads();
    for (int e = tid; e < 32 * 64; e += 256) {
      int s = e >> 6, pp = e & 63;
      xs[s][pp] = xb[((size_t)(b * SEQLEN) + c * CHUNKSZ + s0 + s) * DINNER + h * HEADDIM + pp] * wsh[s];
    }
    for (int e = tid; e < 32 * 128; e += 256) {
      int s = e >> 7, n = e & 127;
      bs[s][n] = bbuf[((size_t)(b * SEQLEN) + c * CHUNKSZ + s0 + s) * DSTATE + n];
    }
    __syncthreads();
#pragma unroll 8
    for (int s = 0; s < 32; ++s) {
      float a[4], bv[8];
#pragma unroll
      for (int i = 0; i < 4; ++i) a[i] = xs[s][tp * 4 + i];
#pragma unroll
      for (int j = 0; j < 8; ++j) bv[j] = bs[s][tn * 8 + j];
#pragma unroll
      for (int i = 0; i < 4; ++i)
#pragma unroll
        for (int j = 0; j < 8; ++j)
          acc[i][j] = fmaf(a[i], bv[j], acc[i][j]);
    }
    __syncthreads();
  }
#pragma unroll
  for (int i = 0; i < 4; ++i)
#pragma unroll
    for (int j = 0; j < 8; ++j)
      states[((size_t)bch * HEADDIM + tp * 4 + i) * DSTATE + tn * 8 + j] = acc[i][j];
}

// ---------------------------------------------------------------------------
// Sequential inter-chunk scan, IN-PLACE.
// ---------------------------------------------------------------------------
__global__ __launch_bounds__(256) void scan_kernel(float* __restrict__ states,
                                                   const float* __restrict__ cdec) {
  int idx = blockIdx.x * 256 + threadIdx.x;
  const int pn = idx & (HEADDIM * DSTATE - 1);
  const int bh = idx >> 13;
  const int h = bh & (NHEADS - 1), b = bh >> 6;
  float S = 0.f;
  for (int c = 0; c < NCHUNK; ++c) {
    int bch = (b * NCHUNK + c) * NHEADS + h;
    size_t off = (size_t)bch * (HEADDIM * DSTATE) + pn;
    float st = states[off];
    states[off] = S;
    S = fmaf(cdec[bch], S, st);
  }
}

// ---------------------------------------------------------------------------
// G0[bc,q,s] = sum_n C[q,n]*B[s,n]  (head-independent, ngroups=1).
// ---------------------------------------------------------------------------
__global__ __launch_bounds__(256) void cb_kernel(const float* __restrict__ cbuf,
                                                 const float* __restrict__ bbuf,
                                                 float* __restrict__ g0) {
  const int qb = blockIdx.x >> 2, sb = blockIdx.x & 3;
  if (sb > qb) return;
  const int bc = blockIdx.y;
  const int tid = threadIdx.x;
  __shared__ float As[16][65];
  __shared__ float Bs[16][65];
  const int lr = tid >> 2, lk = (tid & 3) << 2;
  const int tx = tid & 15, ty = tid >> 4;
  float acc[4][4] = {};
  const float* Arow = cbuf + ((size_t)bc * CHUNKSZ + qb * 64) * DSTATE;
  const float* Brow = bbuf + ((size_t)bc * CHUNKSZ + sb * 64) * DSTATE;
  for (int k0 = 0; k0 < DSTATE; k0 += 16) {
    float4 av = *(const float4*)(Arow + (size_t)lr * DSTATE + k0 + lk);
    float4 bv = *(const float4*)(Brow + (size_t)lr * DSTATE + k0 + lk);
    As[lk + 0][lr] = av.x; As[lk + 1][lr] = av.y; As[lk + 2][lr] = av.z; As[lk + 3][lr] = av.w;
    Bs[lk + 0][lr] = bv.x; Bs[lk + 1][lr] = bv.y; Bs[lk + 2][lr] = bv.z; Bs[lk + 3][lr] = bv.w;
    __syncthreads();
#pragma unroll
    for (int kk = 0; kk < 16; ++kk) {
      float a[4], bv2[4];
#pragma unroll
      for (int i = 0; i < 4; ++i) a[i] = As[kk][ty * 4 + i];
#pragma unroll
      for (int j = 0; j < 4; ++j) bv2[j] = Bs[kk][tx * 4 + j];
#pragma unroll
      for (int i = 0; i < 4; ++i)
#pragma unroll
        for (int j = 0; j < 4; ++j)
          acc[i][j] = fmaf(a[i], bv2[j], acc[i][j]);
    }
    __syncthreads();
  }
#pragma unroll
  for (int i = 0; i < 4; ++i)
#pragma unroll
    for (int j = 0; j < 4; ++j)
      g0[((size_t)bc * CHUNKSZ + qb * 64 + ty * 4 + i) * CHUNKSZ + sb * 64 + tx * 4 + j] = acc[i][j];
}

// ---------------------------------------------------------------------------
// Y[q,p] = diag + off + D*x
// ---------------------------------------------------------------------------
__global__ __launch_bounds__(256) void y_kernel(const float* __restrict__ xb,
                                                const float* __restrict__ cbuf,
                                                const float* __restrict__ g0,
                                                const float* __restrict__ acum,
                                                const float* __restrict__ dtv,
                                                const float* __restrict__ prevb,
                                                const float* __restrict__ Dvec,
                                                float* __restrict__ yb) {
  const int qb = blockIdx.x & 3;
  const int h = (blockIdx.x >> 2) & (NHEADS - 1);
  const int bc = blockIdx.x >> 8;
  const int b = bc >> 3, c = bc & (NCHUNK - 1);
  const int tid = threadIdx.x;
  const int tq = tid >> 4, tp = tid & 15;
  const float* ac = acum + ((size_t)bc * NHEADS + h) * CHUNKSZ;
  __shared__ float gs[64][33];
  __shared__ float xs[32][65];
  __shared__ float ps[64][33];
  const int qbase = qb * 64;
  float acc[4][4] = {};
  for (int s0 = 0; s0 < qbase + 64; s0 += 32) {
    for (int e = tid; e < 64 * 32; e += 256) {
      int q = e >> 5, s = e & 31;
      int gq = qbase + q, gsd = s0 + s;
      float v = 0.f;
      if (gsd <= gq) {
        float lw = expf(ac[gq] - ac[gsd]);
        float dv = dtv[((size_t)(b * SEQLEN) + c * CHUNKSZ + gsd) * NHEADS + h];
        v = g0[((size_t)bc * CHUNKSZ + gq) * CHUNKSZ + gsd] * lw * dv;
      }
      gs[q][s] = v;
    }
    for (int e = tid; e < 32 * 64; e += 256) {
      int s = e >> 6, pp = e & 63;
      xs[s][pp] = xb[((size_t)(b * SEQLEN) + c * CHUNKSZ + s0 + s) * DINNER + h * HEADDIM + pp];
    }
    __syncthreads();
#pragma unroll 8
    for (int s = 0; s < 32; ++s) {
      float a[4], xv[4];
#pragma unroll
      for (int i = 0; i < 4; ++i) a[i] = gs[tq * 4 + i][s];
#pragma unroll
      for (int j = 0; j < 4; ++j) xv[j] = xs[s][tp * 4 + j];
#pragma unroll
      for (int i = 0; i < 4; ++i)
#pragma unroll
        for (int j = 0; j < 4; ++j)
          acc[i][j] = fmaf(a[i], xv[j], acc[i][j]);
    }
    __syncthreads();
  }
  float acc2[4][4] = {};
  for (int n0 = 0; n0 < DSTATE; n0 += 32) {
    for (int e = tid; e < 64 * 32; e += 256) {
      int q = e >> 5, n = e & 31;
      gs[q][n] = cbuf[((size_t)(b * SEQLEN) + c * CHUNKSZ + qbase + q) * DSTATE + n0 + n];
    }
    for (int e = tid; e < 64 * 32; e += 256) {
      int pp = e >> 5, n = e & 31;
      ps[pp][n] = prevb[(((size_t)bc * NHEADS + h) * HEADDIM + pp) * DSTATE + n0 + n];
    }
    __syncthreads();
#pragma unroll 8
    for (int n = 0; n < 32; ++n) {
      float a[4], pv[4];
#pragma unroll
      for (int i = 0; i < 4; ++i) a[i] = gs[tq * 4 + i][n];
#pragma unroll
      for (int j = 0; j < 4; ++j) pv[j] = ps[tp * 4 + j][n];
#pragma unroll
      for (int i = 0; i < 4; ++i)
#pragma unroll
        for (int j = 0; j < 4; ++j)
          acc2[i][j] = fmaf(a[i], pv[j], acc2[i][j]);
    }
    __syncthreads();
  }
  const float dh = Dvec[h];
#pragma unroll
  for (int i = 0; i < 4; ++i) {
    int q = qbase + tq * 4 + i;
    float eaq = expf(ac[q]);
    size_t row = ((size_t)(b * SEQLEN) + c * CHUNKSZ + q) * DINNER + h * HEADDIM;
#pragma unroll
    for (int j = 0; j < 4; ++j) {
      int pp = tp * 4 + j;
      float xv = xb[row + pp];
      yb[row + pp] = acc[i][j] + eaq * acc2[i][j] + dh * xv;
    }
  }
}

// ---------------------------------------------------------------------------
// gated RMSNorm; writes bf16 hi/lo split IN-PLACE over yb's row
// (row read fully before the reduction barrier; writes after it).
// ---------------------------------------------------------------------------
__global__ __launch_bounds__(256) void norm_kernel(float* yb,
                                                   const float* __restrict__ zbuf,
                                                   const float* __restrict__ nw) {
  const int bl = blockIdx.x;
  float* y = yb + (size_t)bl * DINNER;
  const float* z = zbuf + (size_t)bl * DINNER;
  float vals[16];
  float ss = 0.f;
  int j = 0;
  for (int i = threadIdx.x; i < DINNER; i += 256, ++j) {
    float zz = z[i];
    float g = y[i] * zz * sigmoidf_(zz);
    vals[j] = g;
    ss = fmaf(g, g, ss);
  }
  for (int off = 32; off > 0; off >>= 1) ss += __shfl_down(ss, off, 64);
  __shared__ float red[4];
  if ((threadIdx.x & 63) == 0) red[threadIdx.x >> 6] = ss;
  __syncthreads();
  float tot = red[0] + red[1] + red[2] + red[3];
  float scale = rsqrtf(tot * (1.f / DINNER) + EPSV);
  unsigned short* yh = (unsigned short*)y;   // 4096 ushorts = first 2048 floats
  unsigned short* yl = yh + DINNER;          // next 2048 floats
  j = 0;
  for (int i = threadIdx.x; i < DINNER; i += 256, ++j) {
    float v = vals[j] * scale * nw[i];
    unsigned short h = f2bf(v);
    yh[i] = h;
    yl[i] = f2bf(v - bf2f(h));
  }
}

// ---------------------------------------------------------------------------
extern "C" void kernel_launch(void* const* d_in, const int* in_sizes, int n_in,
                              void* d_out, int out_size, void* d_ws, size_t ws_size,
                              hipStream_t stream) {
  const float* u        = (const float*)d_in[0];
  const float* Wp       = (const float*)d_in[1];
  const float* conv_w   = (const float*)d_in[2];
  const float* conv_b   = (const float*)d_in[3];
  const float* dt_bias  = (const float*)d_in[4];
  const float* A_log    = (const float*)d_in[5];
  const float* Dvec     = (const float*)d_in[6];
  const float* norm_w   = (const float*)d_in[7];
  const float* Wo       = (const float*)d_in[8];
  float* out = (float*)d_out;

  char* p = (char*)d_ws;
  auto alloc = [&](size_t nfloats) {
    float* r = (float*)p;
    p += nfloats * sizeof(float);
    return r;
  };
  // static ws total ~213 MB
  float* zbuf   = alloc((size_t)BL * DINNER);                        // 67 MB
  float* xbc    = alloc((size_t)BL * CONVDIM);                       // 71.3 MB
  float* dtraw  = alloc((size_t)BL * NHEADS);                        // 1 MB
  float* xb     = alloc((size_t)BL * DINNER);                        // 67 MB
  float* bbuf   = alloc((size_t)BL * DSTATE);                        // 2 MB
  float* cbuf   = alloc((size_t)BL * DSTATE);                        // 2 MB
  float* dtvb   = alloc((size_t)BL * NHEADS);                        // 1 MB
  float* acum   = alloc((size_t)BATCH * NCHUNK * NHEADS * CHUNKSZ);  // 1 MB
  float* cdec   = alloc((size_t)BATCH * NCHUNK * NHEADS);            // 4 KB
  // overlays (no extra ws):
  float* dAb    = dtraw;                       // elementwise read-then-write
  float* states = out;                         // exact size; dead before step 10
  float* g0     = xbc + (size_t)BL * DINNER;   // xbc tail slack
  float* yb     = xbc;                         // xbc dead after conv
  // bf16 split overlays:
  unsigned short* u_hi  = (unsigned short*)d_out;                 // dead before states
  unsigned short* u_lo  = u_hi + (size_t)BL * DMODEL;             // exactly fills d_out
  unsigned short* wp_hi = (unsigned short*)xb;                    // xb/bbuf/cbuf dead until step 2
  unsigned short* wp_lo = wp_hi + (size_t)DINPROJ * DMODEL;       // 66.5 MiB across xb+bbuf+cbuf
  unsigned short* wo_hi = (unsigned short*)zbuf;                  // zbuf dead after norm
  unsigned short* wo_lo = wo_hi + (size_t)DMODEL * DINNER;
  unsigned short* yo_hi = (unsigned short*)xbc;                   // per-row in-place split
  unsigned short* yo_lo = yo_hi + DINNER;                         // row stride 2*DINNER ushorts

  // 0a. split u -> bf16 hi/lo (in d_out)
  split4_kernel<<<(BL * DMODEL / 4 + 255) / 256, 256, 0, stream>>>(u, u_hi, u_lo, BL * DMODEL / 4);
  // 0b. split Wp -> bf16 hi/lo (in xb region)
  split4_kernel<<<(DINPROJ * DMODEL / 4 + 255) / 256, 256, 0, stream>>>(Wp, wp_hi, wp_lo,
                                                                        DINPROJ * DMODEL / 4);
  // 1. in_proj MFMA GEMM (split epilogue), 1D swizzled grid
  gemm3bf<1><<<((DINPROJ + 127) / 128) * (BL / 128), 256, 0, stream>>>(
      u_hi, u_lo, DMODEL, wp_hi, wp_lo, DMODEL, BL, DINPROJ, DMODEL, zbuf, xbc, dtraw);
  // 2. conv + silu + split
  conv_silu_split<<<(BL * CONVDIM + 255) / 256, 256, 0, stream>>>(xbc, conv_w, conv_b, xb, bbuf, cbuf);
  // 3. dt softplus + dA  (dAb aliases dtraw)
  dt_kernel<<<(BL * NHEADS + 255) / 256, 256, 0, stream>>>(dtraw, dt_bias, A_log, dtvb, dAb);
  // 4. per-chunk cumsum of dA
  cumsum_kernel<<<BATCH * NCHUNK * NHEADS, CHUNKSZ, 0, stream>>>(dAb, acum, cdec);
  // 5. chunk states (in d_out)
  states_kernel<<<BATCH * NCHUNK * NHEADS, 256, 0, stream>>>(xb, bbuf, dtvb, acum, states);
  // 6. inter-chunk scan (in place)
  scan_kernel<<<(BATCH * NHEADS * HEADDIM * DSTATE) / 256, 256, 0, stream>>>(states, cdec);
  // 7. G0 = C.B^T
  cb_kernel<<<dim3(16, BATCH * NCHUNK), 256, 0, stream>>>(cbuf, bbuf, g0);
  // 8. Y = diag + off + D*x
  y_kernel<<<BATCH * NCHUNK * NHEADS * 4, 256, 0, stream>>>(xb, cbuf, g0, acum, dtvb, states, Dvec, yb);
  // 9. gated RMSNorm -> bf16 hi/lo in place over yb rows
  norm_kernel<<<BL, 256, 0, stream>>>(yb, zbuf, norm_w);
  // 9b. split Wo -> bf16 hi/lo (in zbuf region, dead after norm)
  split4_kernel<<<(DMODEL * DINNER / 4 + 255) / 256, 256, 0, stream>>>(Wo, wo_hi, wo_lo,
                                                                      DMODEL * DINNER / 4);
  // 10. out_proj MFMA GEMM -> d_out (states dead), 1D swizzled grid
  gemm3bf<0><<<(DMODEL / 128) * (BL / 128), 256, 0, stream>>>(
      yo_hi, yo_lo, 2 * DINNER, wo_hi, wo_lo, DINNER, BL, DMODEL, DINNER, out, nullptr, nullptr);
}